// Round 16
// baseline (216.942 us; speedup 1.0000x reference)
//
#include <hip/hip_runtime.h>
#include <hip/hip_bf16.h>
#include <stdint.h>

#define NTOK 4096
#define DIM  256
#define NH   8
#define HD   32
#define MAXNNZ 512   // per-row neighbor list capacity (mean ~205)

typedef __attribute__((ext_vector_type(8))) short short8;
typedef __attribute__((ext_vector_type(4))) float float4v;
typedef unsigned short u16;
typedef unsigned int u32;

__device__ __forceinline__ float bf2f(u16 u) {
    union { u32 u; float f; } c; c.u = ((u32)u) << 16; return c.f;
}
__device__ __forceinline__ u16 f2bf(float f) {        // RNE
    union { float f; u32 u; } c; c.f = f;
    u32 u = c.u;
    u = u + 0x7FFFu + ((u >> 16) & 1u);
    return (u16)(u >> 16);
}

// ---------------- kernel A: x (f32) -> bf16 ----------------
__global__ void x_to_bf16(const float* __restrict__ x, u16* __restrict__ xb) {
    int i = (blockIdx.x * blockDim.x + threadIdx.x) * 4;
    float4 v = *(const float4*)(x + i);
    ushort4 o;
    o.x = f2bf(v.x); o.y = f2bf(v.y); o.z = f2bf(v.z); o.w = f2bf(v.w);
    *(ushort4*)(xb + i) = o;
}

// ---------------- kernel 0: transpose weights (f32 256x256 -> bf16 WT) ----------------
__global__ void transpose_w(const float* __restrict__ Wq, const float* __restrict__ Wk,
                            const float* __restrict__ Wv, const float* __restrict__ Wo,
                            u16* __restrict__ WT) {
    const float* srcs[4] = {Wq, Wk, Wv, Wo};
    const float* W = srcs[blockIdx.y];
    int o = blockIdx.x, i = threadIdx.x;
    WT[blockIdx.y * 65536 + o * 256 + i] = f2bf(W[i * 256 + o]);
}

// ---------------- kernel 1: adj (f32) -> per-row neighbor lists ----------------
__global__ __launch_bounds__(256) void adj_to_list(const float* __restrict__ adj,
                                                   u16* __restrict__ NL,
                                                   u32* __restrict__ NC) {
    __shared__ u32 cnt;
    int row = blockIdx.x, t = threadIdx.x;
    if (t == 0) cnt = 0;
    __syncthreads();
    const float4* rp = (const float4*)(adj + (size_t)row * NTOK);
    u16* lbase = NL + (size_t)row * MAXNNZ;
#pragma unroll
    for (int i = 0; i < 4; ++i) {
        float4 v = rp[i * 256 + t];
        u32 m = 0;
        if (v.x != 0.f) m |= 1u;
        if (v.y != 0.f) m |= 2u;
        if (v.z != 0.f) m |= 4u;
        if (v.w != 0.f) m |= 8u;
        if (m) {
            int p = __popc(m);
            u32 base = atomicAdd(&cnt, (u32)p);
            int col0 = (i * 256 + t) * 4;
            while (m) {
                int j = __builtin_ctz(m);
                m &= m - 1;
                if (base < MAXNNZ) lbase[base] = (u16)(col0 + j);
                ++base;
            }
        }
    }
    __syncthreads();
    if (t == 0) NC[row] = (cnt < MAXNNZ) ? cnt : MAXNNZ;
}

// ---------------- kernel 2: QKV projection -> Q + interleaved KV rows ----------------
// mat 0 -> Q (pre-scaled by 1/sqrt(HD)*log2e); mat 1 -> KV[m][0..255] (K);
// mat 2 -> KV[m][256..511] (V). KV row stride = 512 elems (1 KB).
__global__ __launch_bounds__(64) void qkv_gemm(
    const u16* __restrict__ xb,
    const u16* __restrict__ WT,
    const float* __restrict__ bq, const float* __restrict__ bk, const float* __restrict__ bv,
    u16* __restrict__ Q, u16* __restrict__ KV) {
    int lane = threadIdx.x, quad = lane >> 4, l16 = lane & 15;
    int mtile = blockIdx.x, ntile = blockIdx.y, mat = blockIdx.z;
    const float* bias = (mat == 0) ? bq : (mat == 1) ? bk : bv;
    const u16* arow = xb + (size_t)(mtile * 16 + l16) * DIM + quad * 8;
    const u16* brow = WT + (size_t)mat * 65536 + (size_t)(ntile * 16 + l16) * DIM + quad * 8;
    float4v acc = {0.f, 0.f, 0.f, 0.f};
#pragma unroll
    for (int k0 = 0; k0 < DIM; k0 += 32) {
        short8 af = *(const short8*)(arow + k0);
        short8 bf = *(const short8*)(brow + k0);
        acc = __builtin_amdgcn_mfma_f32_16x16x32_bf16(af, bf, acc, 0, 0, 0);
    }
    int n = ntile * 16 + l16;
    float bb = bias[n];
    const float sc = (mat == 0) ? 0.25503635559913516f : 1.0f;  // 1/sqrt(32)*log2e
#pragma unroll
    for (int r = 0; r < 4; ++r) {
        int m = mtile * 16 + quad * 4 + r;
        u16 o = f2bf((acc[r] + bb) * sc);
        if (mat == 0)      Q[(size_t)m * DIM + n] = o;
        else if (mat == 1) KV[(size_t)m * 512 + n] = o;
        else               KV[(size_t)m * 512 + 256 + n] = o;
    }
}

// ---------------- kernel 3: SPARSE attention, interleaved-KV 8-batch gather ----------------
// One wave per query row (all 8 heads). Lane l: dims 4l..4l+3; head = l>>3.
// Per neighbor: ONE base address into KV (idx<<9 + l4); K at +0, V at +256 elems
// (512 B instruction-immediate offset). 16 gathers in flight per 8-neighbor batch.
__global__ __launch_bounds__(256, 4) void sparse_attn(
    const u16* __restrict__ Q, const u16* __restrict__ KV,
    const u16* __restrict__ NL, const u32* __restrict__ NC,
    u16* __restrict__ AO) {
    int row = blockIdx.x * 4 + (threadIdx.x >> 6);
    int lane = threadIdx.x & 63;
    int l4 = lane * 4;

    ushort4 qu = *(const ushort4*)(Q + (size_t)row * DIM + l4);
    float q0 = bf2f(qu.x), q1 = bf2f(qu.y), q2 = bf2f(qu.z), q3 = bf2f(qu.w);
    float O0 = 0.f, O1 = 0.f, O2 = 0.f, O3 = 0.f, lsum = 0.f;

    int nnz = (int)NC[row];
    const u16* lst = NL + (size_t)row * MAXNNZ;

#define NBR_BODY(kk, vv)                                                          \
    {                                                                             \
        float s = q0 * bf2f(kk.x) + q1 * bf2f(kk.y)                               \
                + q2 * bf2f(kk.z) + q3 * bf2f(kk.w);                              \
        s += __shfl_xor(s, 1, 64);                                                \
        s += __shfl_xor(s, 2, 64);                                                \
        s += __shfl_xor(s, 4, 64);                                                \
        float e = __builtin_amdgcn_exp2f(s);                                      \
        lsum += e;                                                                \
        O0 += e * bf2f(vv.x); O1 += e * bf2f(vv.y);                               \
        O2 += e * bf2f(vv.z); O3 += e * bf2f(vv.w);                               \
    }

    int j = 0;
    for (; j + 8 <= nnz; j += 8) {
        ushort4 i03 = *(const ushort4*)(lst + j);
        ushort4 i47 = *(const ushort4*)(lst + j + 4);
        const u16* b0 = KV + ((size_t)i03.x << 9) + l4;
        const u16* b1 = KV + ((size_t)i03.y << 9) + l4;
        const u16* b2 = KV + ((size_t)i03.z << 9) + l4;
        const u16* b3 = KV + ((size_t)i03.w << 9) + l4;
        const u16* b4 = KV + ((size_t)i47.x << 9) + l4;
        const u16* b5 = KV + ((size_t)i47.y << 9) + l4;
        const u16* b6 = KV + ((size_t)i47.z << 9) + l4;
        const u16* b7 = KV + ((size_t)i47.w << 9) + l4;
        ushort4 kk[8], vv[8];
        kk[0] = *(const ushort4*)(b0); vv[0] = *(const ushort4*)(b0 + 256);
        kk[1] = *(const ushort4*)(b1); vv[1] = *(const ushort4*)(b1 + 256);
        kk[2] = *(const ushort4*)(b2); vv[2] = *(const ushort4*)(b2 + 256);
        kk[3] = *(const ushort4*)(b3); vv[3] = *(const ushort4*)(b3 + 256);
        kk[4] = *(const ushort4*)(b4); vv[4] = *(const ushort4*)(b4 + 256);
        kk[5] = *(const ushort4*)(b5); vv[5] = *(const ushort4*)(b5 + 256);
        kk[6] = *(const ushort4*)(b6); vv[6] = *(const ushort4*)(b6 + 256);
        kk[7] = *(const ushort4*)(b7); vv[7] = *(const ushort4*)(b7 + 256);
#pragma unroll
        for (int t = 0; t < 8; ++t) NBR_BODY(kk[t], vv[t])
    }
    for (; j < nnz; ++j) {
        const u16* b0 = KV + ((size_t)lst[j] << 9) + l4;
        ushort4 k0 = *(const ushort4*)(b0), v0 = *(const ushort4*)(b0 + 256);
        NBR_BODY(k0, v0)
    }
#undef NBR_BODY

    float inv = 1.0f / lsum;
    ushort4 o;
    o.x = f2bf(O0 * inv); o.y = f2bf(O1 * inv);
    o.z = f2bf(O2 * inv); o.w = f2bf(O3 * inv);
    *(ushort4*)(AO + (size_t)row * DIM + l4) = o;
}

// ---------------- kernel 4: output projection (f32 out) ----------------
__global__ __launch_bounds__(64) void out_gemm(
    const u16* __restrict__ AO, const u16* __restrict__ WTo, const float* __restrict__ bo,
    float* __restrict__ out) {
    int lane = threadIdx.x, quad = lane >> 4, l16 = lane & 15;
    int mtile = blockIdx.x, ntile = blockIdx.y;
    const u16* arow = AO + (size_t)(mtile * 16 + l16) * DIM + quad * 8;
    const u16* brow = WTo + (size_t)(ntile * 16 + l16) * DIM + quad * 8;
    float4v acc = {0.f, 0.f, 0.f, 0.f};
#pragma unroll
    for (int k0 = 0; k0 < DIM; k0 += 32) {
        short8 af = *(const short8*)(arow + k0);
        short8 bf = *(const short8*)(brow + k0);
        acc = __builtin_amdgcn_mfma_f32_16x16x32_bf16(af, bf, acc, 0, 0, 0);
    }
    int n = ntile * 16 + l16;
    float bb = bo[n];
#pragma unroll
    for (int r = 0; r < 4; ++r)
        out[(size_t)(mtile * 16 + quad * 4 + r) * DIM + n] = acc[r] + bb;
}

extern "C" void kernel_launch(void* const* d_in, const int* in_sizes, int n_in,
                              void* d_out, int out_size, void* d_ws, size_t ws_size,
                              hipStream_t stream) {
    const float* x   = (const float*)d_in[0];
    const float* adj = (const float*)d_in[1];
    const float* Wq  = (const float*)d_in[2];
    const float* bq  = (const float*)d_in[3];
    const float* Wk  = (const float*)d_in[4];
    const float* bk  = (const float*)d_in[5];
    const float* Wv  = (const float*)d_in[6];
    const float* bv  = (const float*)d_in[7];
    const float* Wo  = (const float*)d_in[8];
    const float* bo  = (const float*)d_in[9];

    char* ws = (char*)d_ws;
    const size_t MB = 1u << 20;
    u16* Q   = (u16*)(ws);                          // 2 MB
    u16* KV  = (u16*)(ws + 2 * MB);                 // 4 MB interleaved K|V rows
    u16* AO  = (u16*)(ws + 6 * MB);                 // 2 MB
    u16* WT  = (u16*)(ws + 8 * MB);                 // 512 KB
    u16* XB  = (u16*)(ws + 8 * MB + 512 * 1024);    // 2 MB
    u16* NL  = (u16*)(ws + 11 * MB);                // 4 MB neighbor lists
    u32* NC  = (u32*)(ws + 15 * MB);                // 16 KB counts

    x_to_bf16<<<dim3(1024), 256, 0, stream>>>(x, XB);
    transpose_w<<<dim3(256, 4), 256, 0, stream>>>(Wq, Wk, Wv, Wo, WT);
    adj_to_list<<<dim3(4096), 256, 0, stream>>>(adj, NL, NC);
    qkv_gemm<<<dim3(256, 16, 3), 64, 0, stream>>>(XB, WT, bq, bk, bv, Q, KV);
    sparse_attn<<<dim3(1024), 256, 0, stream>>>(Q, KV, NL, NC, AO);
    out_gemm<<<dim3(256, 16), 64, 0, stream>>>(AO, WT + 3 * 65536, bo, (float*)d_out);
}